// Round 9
// baseline (352.878 us; speedup 1.0000x reference)
//
#include <hip/hip_runtime.h>
#include <hip/hip_bf16.h>
#include <math.h>

#define N_NODES 50000
#define N_EDGES 800000
#define IN_DIM  128
#define MEM_DIM 32
#define OUT_DIM 64
#define NB_SCAN ((N_NODES + 255) / 256)   // 196
#define SCALE   0.17677669529663687f      // 1/sqrt(32)

typedef __attribute__((ext_vector_type(8))) short bf16x8;
typedef __attribute__((ext_vector_type(4))) float f32x4;

__device__ __forceinline__ short f2bf(float f) {
    union { float f; unsigned u; } v; v.f = f;
    unsigned r = v.u + 0x7FFF + ((v.u >> 16) & 1);   // round-to-nearest-even
    return (short)(r >> 16);
}
__device__ __forceinline__ float lo16(unsigned u) { return __uint_as_float(u << 16); }
__device__ __forceinline__ float hi16(unsigned u) { return __uint_as_float(u & 0xffff0000u); }

// ---------------------------------------------------------------------------
// prep_k: build transposed bf16 weight bank wtb[m][col][k] (col-major rows so
// a B-frag = 8 contiguous bf16 = ONE dwordx4). m: 0=Wq*S, 1=Wk, 2=Wv,
// 3=Wskip, 4=WqE*S (We_k folded into Wq). ALSO zeroes the 8-replica cntr
// (folds the memset dispatch).
// ---------------------------------------------------------------------------
__global__ __launch_bounds__(256) void prep_k(
    const float* __restrict__ Wq, const float* __restrict__ Wk,
    const float* __restrict__ Wv, const float* __restrict__ Wskip,
    const float* __restrict__ We_k, unsigned short* __restrict__ wtb,
    int* __restrict__ cntr)
{
    const int i = blockIdx.x * 256 + threadIdx.x;   // 1600*256 = 409600
    if (i < 8 * N_NODES) cntr[i] = 0;
    if (i >= 51200) return;                         // 5*64*160
    const int m = i / 10240, rem = i % 10240, c = rem / 160, k = rem % 160;
    float v;
    if (m == 4) {
        const int h = c >> 5, kk = c & 31;
        v = 0.f;
        #pragma unroll
        for (int j = 0; j < 32; ++j)
            v += Wq[k * 64 + h * 32 + j] * We_k[kk * 64 + h * 32 + j];
        v *= SCALE;
    } else {
        const float* W = (m == 0) ? Wq : (m == 1) ? Wk : (m == 2) ? Wv : Wskip;
        v = W[k * 64 + c];
        if (m == 0) v *= SCALE;
    }
    wtb[(size_t)(m * 64 + c) * 160 + k] = (unsigned short)f2bf(v);
}

// ---------------------------------------------------------------------------
// Kernel A: node GEMM [N,160]@[160, 5x64] -> zqp (bf16 q*S), zkv (bf16 k||v),
// qekp (bf16 (z@WqE)*S), out (skip, f32). 5 waves; wave = matrix; B-frags are
// single 16B loads from wtb. FUSED: 8-replica dst histogram (replica =
// blockIdx&7 — XCD-local lines) + rank capture on threads 0..255.
// ---------------------------------------------------------------------------
__global__ __launch_bounds__(320) void node_gemm(
    const float* __restrict__ x, const float* __restrict__ mem,
    const unsigned short* __restrict__ wtb,
    const int* __restrict__ dstE, int* __restrict__ cntr, int* __restrict__ rank,
    unsigned short* __restrict__ zqp, unsigned short* __restrict__ zkv,
    unsigned short* __restrict__ qekp, float* __restrict__ out)
{
    const int tid  = threadIdx.x;
    if (tid < 256) {
        const int e = blockIdx.x * 256 + tid;   // 3125*256 == E
        rank[e] = atomicAdd(&cntr[(blockIdx.x & 7) * N_NODES + dstE[e]], 1);
    }

    const int w    = tid >> 6;                  // 0..4
    const int lane = tid & 63;
    const int l15  = lane & 15;
    const int quad = lane >> 4;
    const int nb   = blockIdx.x * 16;

    const unsigned short* WmT = wtb + (size_t)w * 64 * 160;

    f32x4 acc[4];
    #pragma unroll
    for (int g = 0; g < 4; ++g) acc[g] = (f32x4)0.0f;

    const int node = nb + l15;
    #pragma unroll
    for (int kb = 0; kb < 5; ++kb) {
        const float* zsrc = (kb < 4)
            ? (x   + (size_t)node * IN_DIM  + kb * 32 + quad * 8)
            : (mem + (size_t)node * MEM_DIM + quad * 8);
        bf16x8 afrag;
        #pragma unroll
        for (int j = 0; j < 8; ++j) afrag[j] = f2bf(zsrc[j]);

        const int k0 = kb * 32 + quad * 8;
        #pragma unroll
        for (int g = 0; g < 4; ++g) {
            const bf16x8 bfrag = *(const bf16x8*)(WmT + (size_t)(16 * g + l15) * 160 + k0);
            acc[g] = __builtin_amdgcn_mfma_f32_16x16x32_bf16(afrag, bfrag, acc[g], 0, 0, 0);
        }
    }
    #pragma unroll
    for (int g = 0; g < 4; ++g) {
        #pragma unroll
        for (int r = 0; r < 4; ++r) {
            const int nrow = nb + quad * 4 + r;
            const int col  = 16 * g + l15;
            if (w == 3)
                out[(size_t)nrow * OUT_DIM + col] = acc[g][r];
            else if (w == 0)
                zqp[(size_t)nrow * 64 + col] = (unsigned short)f2bf(acc[g][r]);
            else if (w == 4)
                qekp[(size_t)nrow * 64 + col] = (unsigned short)f2bf(acc[g][r]);
            else
                zkv[(size_t)nrow * 128 + (w == 2 ? 64 : 0) + col] =
                    (unsigned short)f2bf(acc[g][r]);
        }
    }
}

// ---------------------------------------------------------------------------
// scan1: per node, reduce the 8 replica counts -> in-place exclusive replica
// offsets + deg; then block-exclusive-scan of totals. scan2: scan block sums.
// ---------------------------------------------------------------------------
__global__ __launch_bounds__(256) void scan1_k(int* __restrict__ cntr,
                                               int* __restrict__ base,
                                               int* __restrict__ bsum,
                                               int* __restrict__ deg)
{
    __shared__ int sh[256];
    const int i = blockIdx.x * 256 + threadIdx.x;
    int tot = 0;
    if (i < N_NODES) {
        int off = 0;
        #pragma unroll
        for (int r = 0; r < 8; ++r) {
            const int c = cntr[r * N_NODES + i];
            cntr[r * N_NODES + i] = off;
            off += c;
        }
        tot = off;
        deg[i] = tot;
    }
    sh[threadIdx.x] = tot;
    __syncthreads();
    int val = tot;
    for (int off = 1; off < 256; off <<= 1) {
        const int y = (threadIdx.x >= off) ? sh[threadIdx.x - off] : 0;
        __syncthreads();
        val += y; sh[threadIdx.x] = val;
        __syncthreads();
    }
    if (i < N_NODES) base[i] = val - tot;
    if (threadIdx.x == 255) bsum[blockIdx.x] = val;
}

__global__ __launch_bounds__(256) void scan2_k(int* __restrict__ bsum)
{
    __shared__ int sh[256];
    const int i = threadIdx.x;
    const int v = (i < NB_SCAN) ? bsum[i] : 0;
    sh[i] = v;
    __syncthreads();
    int val = v;
    for (int off = 1; off < 256; off <<= 1) {
        const int y = (i >= off) ? sh[i - off] : 0;
        __syncthreads();
        val += y; sh[i] = val;
        __syncthreads();
    }
    if (i < NB_SCAN) bsum[i] = val - v;
}

// ---------------------------------------------------------------------------
// Atomic-free scatter: pos = base[d] + bsum[d>>8] + replica_off + rank[e]
// ---------------------------------------------------------------------------
__global__ __launch_bounds__(256) void scatter_k(
    const int* __restrict__ src, const int* __restrict__ dst,
    const float* __restrict__ t, const int* __restrict__ base,
    const int* __restrict__ bsum, const int* __restrict__ cntr,
    const int* __restrict__ rank, int2* __restrict__ edata)
{
    const int e = blockIdx.x * 256 + threadIdx.x;
    const int d = dst[e];
    const int pos = base[d] + bsum[d >> 8]
                  + cntr[(blockIdx.x & 7) * N_NODES + d] + rank[e];
    edata[pos] = make_int2(src[e], __float_as_int(t[e]));
}

// ---------------------------------------------------------------------------
// Kernel B: one WAVE per node. Score: chunk of 16 edges, 4 lanes/edge
// (lane = eidx + 16*g; group g covers k-dims [16g,16g+16)). Agg: srcn/pe
// distributed by REGISTER SHUFFLES (edge j's srcn is in lane j, pe in lane
// j / j+32; invalid slots have pe==0) -> 16 independent v-loads batch-issued
// per chunk instead of a 16-deep LDS->load->FMA chain. LDS only stages the
// 64-float pte vector for the fused We_v epilogue. No atomics.
// ---------------------------------------------------------------------------
__global__ __launch_bounds__(256) void gather_edge(
    const int2* __restrict__ edata, const int* __restrict__ base,
    const int* __restrict__ bsum, const int* __restrict__ degA,
    const float* __restrict__ w_time, const float* __restrict__ b_time,
    const unsigned short* __restrict__ zqp,
    const unsigned short* __restrict__ qekp,
    const unsigned short* __restrict__ zkv,
    const float* __restrict__ We_v, float* __restrict__ out)
{
    __shared__ float recs[4][64];               // 1 KB; wave-private pte stage
    const int tid  = threadIdx.x;
    const int w    = tid >> 6;
    const int lane = tid & 63;
    const int eidx = lane & 15;
    const int g    = lane >> 4;
    const int n    = blockIdx.x * 4 + w;

    const int b0  = base[n] + bsum[n >> 8];
    const int deg = degA[n];
    float* rec = &recs[w][0];

    // this group's 16 te params (per-head te index = 16*(g&1)+i)
    const int hk16 = (g & 1) * 16;
    float wts[16], bts[16];
    #pragma unroll
    for (int i = 0; i < 16; ++i) {
        wts[i] = w_time[hk16 + i];
        bts[i] = b_time[hk16 + i];
    }

    // q/qek: this lane's 16 dims [16g,+16), bf16 pairs, prescaled by 1/sqrt32
    unsigned q2[8], qe2[8];
    {
        const uint4* qP  = (const uint4*)(zqp  + (size_t)n * 64 + 16 * g);
        const uint4* qeP = (const uint4*)(qekp + (size_t)n * 64 + 16 * g);
        const uint4 a0 = qP[0],  a1 = qP[1];
        const uint4 b0v = qeP[0], b1v = qeP[1];
        q2[0]=a0.x; q2[1]=a0.y; q2[2]=a0.z; q2[3]=a0.w;
        q2[4]=a1.x; q2[5]=a1.y; q2[6]=a1.z; q2[7]=a1.w;
        qe2[0]=b0v.x; qe2[1]=b0v.y; qe2[2]=b0v.z; qe2[3]=b0v.w;
        qe2[4]=b1v.x; qe2[5]=b1v.y; qe2[6]=b1v.z; qe2[7]=b1v.w;
    }

    float av = 0.f, lpacc = 0.f;
    float ptep[16];
    #pragma unroll
    for (int i = 0; i < 16; ++i) ptep[i] = 0.f;

    for (int ch = 0; ch < deg; ch += 16) {
        // ---- score: 4 lanes per edge ----
        const int el = b0 + ch + eidx;
        const int2 ed = edata[min(el, N_EDGES - 1)];
        const float tv = __int_as_float(ed.y);
        const bool valid = (ch + eidx) < deg;

        const uint4* kP = (const uint4*)(zkv + (size_t)ed.x * 128 + 16 * g);
        const uint4 k0v = kP[0], k1v = kP[1];
        unsigned kk[8];
        kk[0]=k0v.x; kk[1]=k0v.y; kk[2]=k0v.z; kk[3]=k0v.w;
        kk[4]=k1v.x; kk[5]=k1v.y; kk[6]=k1v.z; kk[7]=k1v.w;

        float te[16];
        float p = 0.f;
        #pragma unroll
        for (int i2 = 0; i2 < 8; ++i2) {
            te[2*i2]   = __cosf(tv * wts[2*i2]   + bts[2*i2]);
            te[2*i2+1] = __cosf(tv * wts[2*i2+1] + bts[2*i2+1]);
            p += te[2*i2] * lo16(qe2[i2]) + te[2*i2+1] * hi16(qe2[i2]);
            p += lo16(q2[i2]) * lo16(kk[i2]) + hi16(q2[i2]) * hi16(kk[i2]);
        }
        p += __shfl_xor(p, 16, 64);             // combine the head's 2 groups
        const float pe = valid ? __expf(p) : 0.f;   // scale pre-folded

        #pragma unroll
        for (int i = 0; i < 16; ++i) ptep[i] += pe * te[i];   // head g>>1

        if ((g & 1) == 0) lpacc += pe;          // g==0 -> head0, g==2 -> head1

        // ---- agg: shuffle-distributed, batch-issued v gathers ----
        // edge j: srcn in lane j (all groups loaded it), pe in lane j (head0)
        // and lane j+32 (head1); pe==0 for invalid slots -> no masking.
        #pragma unroll
        for (int j = 0; j < 16; ++j) {
            const int   sj = __shfl(ed.x, j, 64);
            const float pj = __shfl(pe, j + (lane & 32), 64);
            const float v  = lo16((unsigned)zkv[(size_t)sj * 128 + 64 + lane]);
            av += pj * v;
        }
    }

    // ---- epilogue ----
    #pragma unroll
    for (int off = 1; off < 16; off <<= 1)
        #pragma unroll
        for (int i = 0; i < 16; ++i) ptep[i] += __shfl_xor(ptep[i], off, 64);
    lpacc += __shfl_xor(lpacc, 1, 64);
    lpacc += __shfl_xor(lpacc, 2, 64);
    lpacc += __shfl_xor(lpacc, 4, 64);
    lpacc += __shfl_xor(lpacc, 8, 64);
    // stage pte: rec[h*32+d] (g0: h0 d0-15, g1: h0 d16-31, g2/g3: h1)
    if (eidx == 0) {
        #pragma unroll
        for (int i = 0; i < 16; ++i) rec[g * 16 + i] = ptep[i];
    }
    float wev[32];
    #pragma unroll
    for (int k = 0; k < 32; ++k) wev[k] = We_v[k * 64 + lane];

    const float l   = __shfl(lpacc, lane & 32, 64);
    const float inv = (l > 0.f) ? 1.f / l : 0.f;
    const float* pl = rec + (lane >> 5) * 32;
    float dot = 0.f;
    #pragma unroll
    for (int k = 0; k < 32; ++k) dot += pl[k] * wev[k];

    out[(size_t)n * OUT_DIM + lane] += (av + dot) * inv;   // skip already there
}

extern "C" void kernel_launch(void* const* d_in, const int* in_sizes, int n_in,
                              void* d_out, int out_size, void* d_ws, size_t ws_size,
                              hipStream_t stream) {
    (void)in_sizes; (void)n_in; (void)out_size; (void)ws_size;
    const int*   src    = (const int*)d_in[0];
    const int*   dst    = (const int*)d_in[1];
    const float* t      = (const float*)d_in[2];
    const float* x      = (const float*)d_in[3];
    const float* mem    = (const float*)d_in[4];
    const float* w_time = (const float*)d_in[5];
    const float* b_time = (const float*)d_in[6];
    const float* Wq     = (const float*)d_in[7];
    const float* Wk     = (const float*)d_in[8];
    const float* Wv     = (const float*)d_in[9];
    const float* We_k   = (const float*)d_in[10];
    const float* We_v   = (const float*)d_in[11];
    const float* Wskip  = (const float*)d_in[12];

    // workspace layout (16B-aligned chunks)
    char* p = (char*)d_ws;
    unsigned short* zkv  = (unsigned short*)p; p += (size_t)N_NODES * 128 * 2; // 12.8 MB
    unsigned short* zqp  = (unsigned short*)p; p += (size_t)N_NODES * 64 * 2;  // 6.4 MB
    unsigned short* qekp = (unsigned short*)p; p += (size_t)N_NODES * 64 * 2;  // 6.4 MB
    unsigned short* wtb  = (unsigned short*)p; p += (size_t)5 * 64 * 160 * 2;  // 100 KB
    int2* edata = (int2*)p;  p += (size_t)N_EDGES * 8;                         // 6.4 MB
    int*  cntr  = (int*)p;   p += (size_t)8 * N_NODES * 4;   // 1.6 MB (zeroed in prep_k)
    int*  rank  = (int*)p;   p += (size_t)N_EDGES * 4;
    int*  base  = (int*)p;   p += (size_t)N_NODES * 4;
    int*  deg   = (int*)p;   p += (size_t)N_NODES * 4;
    int*  bsum  = (int*)p;   p += 256 * 4;
    float* out  = (float*)d_out;

    prep_k   <<<1600, 256, 0, stream>>>(Wq, Wk, Wv, Wskip, We_k, wtb, cntr);
    node_gemm<<<N_NODES / 16, 320, 0, stream>>>(x, mem, wtb, dst, cntr, rank,
                                                zqp, zkv, qekp, out);
    scan1_k  <<<NB_SCAN, 256, 0, stream>>>(cntr, base, bsum, deg);
    scan2_k  <<<1, 256, 0, stream>>>(bsum);
    scatter_k<<<N_EDGES / 256, 256, 0, stream>>>(src, dst, t, base, bsum, cntr,
                                                 rank, edata);
    gather_edge<<<N_NODES / 4, 256, 0, stream>>>(edata, base, bsum, deg,
                                                 w_time, b_time, zqp, qekp, zkv,
                                                 We_v, out);
}

// Round 10
// 272.449 us; speedup vs baseline: 1.2952x; 1.2952x over previous
//
#include <hip/hip_runtime.h>
#include <hip/hip_bf16.h>
#include <math.h>

#define N_NODES 50000
#define N_EDGES 800000
#define IN_DIM  128
#define MEM_DIM 32
#define OUT_DIM 64
#define NB_SCAN ((N_NODES + 255) / 256)   // 196
#define SCALE   0.17677669529663687f      // 1/sqrt(32)

typedef __attribute__((ext_vector_type(8))) short bf16x8;
typedef __attribute__((ext_vector_type(4))) float f32x4;

__device__ __forceinline__ short f2bf(float f) {
    union { float f; unsigned u; } v; v.f = f;
    unsigned r = v.u + 0x7FFF + ((v.u >> 16) & 1);   // round-to-nearest-even
    return (short)(r >> 16);
}
__device__ __forceinline__ float lo16(unsigned u) { return __uint_as_float(u << 16); }
__device__ __forceinline__ float hi16(unsigned u) { return __uint_as_float(u & 0xffff0000u); }

// ---------------------------------------------------------------------------
// prep_k: transposed bf16 weight bank wtb[m][col][k] (B-frag = one dwordx4).
// m: 0=Wq*S, 1=Wk, 2=Wv, 3=Wskip, 4=WqE*S (We_k folded into Wq). Also zeroes
// the 8-replica histogram.
// ---------------------------------------------------------------------------
__global__ __launch_bounds__(256) void prep_k(
    const float* __restrict__ Wq, const float* __restrict__ Wk,
    const float* __restrict__ Wv, const float* __restrict__ Wskip,
    const float* __restrict__ We_k, unsigned short* __restrict__ wtb,
    int* __restrict__ cntr)
{
    const int i = blockIdx.x * 256 + threadIdx.x;   // 1600*256 = 409600
    if (i < 8 * N_NODES) cntr[i] = 0;
    if (i >= 51200) return;                         // 5*64*160
    const int m = i / 10240, rem = i % 10240, c = rem / 160, k = rem % 160;
    float v;
    if (m == 4) {
        const int h = c >> 5, kk = c & 31;
        v = 0.f;
        #pragma unroll
        for (int j = 0; j < 32; ++j)
            v += Wq[k * 64 + h * 32 + j] * We_k[kk * 64 + h * 32 + j];
        v *= SCALE;
    } else {
        const float* W = (m == 0) ? Wq : (m == 1) ? Wk : (m == 2) ? Wv : Wskip;
        v = W[k * 64 + c];
        if (m == 0) v *= SCALE;
    }
    wtb[(size_t)(m * 64 + c) * 160 + k] = (unsigned short)f2bf(v);
}

// ---------------------------------------------------------------------------
// Kernel A: PURE node GEMM [N,160]@[160, 5x64] -> zqp, zkv, qekp (bf16),
// out (skip, f32). 5 waves; wave = matrix; B-frags single 16B loads.
// (Histogram de-fused this round to expose its true cost.)
// ---------------------------------------------------------------------------
__global__ __launch_bounds__(320) void node_gemm(
    const float* __restrict__ x, const float* __restrict__ mem,
    const unsigned short* __restrict__ wtb,
    unsigned short* __restrict__ zqp, unsigned short* __restrict__ zkv,
    unsigned short* __restrict__ qekp, float* __restrict__ out)
{
    const int tid  = threadIdx.x;
    const int w    = tid >> 6;                  // 0..4
    const int lane = tid & 63;
    const int l15  = lane & 15;
    const int quad = lane >> 4;
    const int nb   = blockIdx.x * 16;

    const unsigned short* WmT = wtb + (size_t)w * 64 * 160;

    f32x4 acc[4];
    #pragma unroll
    for (int g = 0; g < 4; ++g) acc[g] = (f32x4)0.0f;

    const int node = nb + l15;
    #pragma unroll
    for (int kb = 0; kb < 5; ++kb) {
        const float* zsrc = (kb < 4)
            ? (x   + (size_t)node * IN_DIM  + kb * 32 + quad * 8)
            : (mem + (size_t)node * MEM_DIM + quad * 8);
        bf16x8 afrag;
        #pragma unroll
        for (int j = 0; j < 8; ++j) afrag[j] = f2bf(zsrc[j]);

        const int k0 = kb * 32 + quad * 8;
        #pragma unroll
        for (int g = 0; g < 4; ++g) {
            const bf16x8 bfrag = *(const bf16x8*)(WmT + (size_t)(16 * g + l15) * 160 + k0);
            acc[g] = __builtin_amdgcn_mfma_f32_16x16x32_bf16(afrag, bfrag, acc[g], 0, 0, 0);
        }
    }
    #pragma unroll
    for (int g = 0; g < 4; ++g) {
        #pragma unroll
        for (int r = 0; r < 4; ++r) {
            const int nrow = nb + quad * 4 + r;
            const int col  = 16 * g + l15;
            if (w == 3)
                out[(size_t)nrow * OUT_DIM + col] = acc[g][r];
            else if (w == 0)
                zqp[(size_t)nrow * 64 + col] = (unsigned short)f2bf(acc[g][r]);
            else if (w == 4)
                qekp[(size_t)nrow * 64 + col] = (unsigned short)f2bf(acc[g][r]);
            else
                zkv[(size_t)nrow * 128 + (w == 2 ? 64 : 0) + col] =
                    (unsigned short)f2bf(acc[g][r]);
        }
    }
}

// ---------------------------------------------------------------------------
// hist_k: 8-replica dst histogram + rank capture. replica = (e>>8)&7.
// ---------------------------------------------------------------------------
__global__ __launch_bounds__(256) void hist_k(
    const int* __restrict__ dst, int* __restrict__ cntr, int* __restrict__ rank)
{
    const int e = blockIdx.x * 256 + threadIdx.x;   // 3125*256 == E
    rank[e] = atomicAdd(&cntr[(blockIdx.x & 7) * N_NODES + dst[e]], 1);
}

// ---------------------------------------------------------------------------
// scan1: reduce 8 replica counts -> in-place exclusive replica offsets + deg;
// block-exclusive-scan of totals. scan2: scan the 196 block sums.
// ---------------------------------------------------------------------------
__global__ __launch_bounds__(256) void scan1_k(int* __restrict__ cntr,
                                               int* __restrict__ base,
                                               int* __restrict__ bsum,
                                               int* __restrict__ deg)
{
    __shared__ int sh[256];
    const int i = blockIdx.x * 256 + threadIdx.x;
    int tot = 0;
    if (i < N_NODES) {
        int off = 0;
        #pragma unroll
        for (int r = 0; r < 8; ++r) {
            const int c = cntr[r * N_NODES + i];
            cntr[r * N_NODES + i] = off;
            off += c;
        }
        tot = off;
        deg[i] = tot;
    }
    sh[threadIdx.x] = tot;
    __syncthreads();
    int val = tot;
    for (int off = 1; off < 256; off <<= 1) {
        const int y = (threadIdx.x >= off) ? sh[threadIdx.x - off] : 0;
        __syncthreads();
        val += y; sh[threadIdx.x] = val;
        __syncthreads();
    }
    if (i < N_NODES) base[i] = val - tot;
    if (threadIdx.x == 255) bsum[blockIdx.x] = val;
}

__global__ __launch_bounds__(256) void scan2_k(int* __restrict__ bsum)
{
    __shared__ int sh[256];
    const int i = threadIdx.x;
    const int v = (i < NB_SCAN) ? bsum[i] : 0;
    sh[i] = v;
    __syncthreads();
    int val = v;
    for (int off = 1; off < 256; off <<= 1) {
        const int y = (i >= off) ? sh[i - off] : 0;
        __syncthreads();
        val += y; sh[i] = val;
        __syncthreads();
    }
    if (i < NB_SCAN) bsum[i] = val - v;
}

// ---------------------------------------------------------------------------
// score_scatter_k: EDGE-parallel over raw edges (dense, no per-node loops).
// 4 lanes/edge (lane = eidx + 16*g; group g covers k-dims [16g,16g+16)).
// Gathers k[src] (2x16B/lane) + q/qek[dst] (2x16B/lane), computes pe per
// head, and writes the record (src, t, pe0, pe1) DIRECTLY to its dst-sorted
// slot (absorbs scatter_k; edata never roundtrips in unsorted form).
// ---------------------------------------------------------------------------
__global__ __launch_bounds__(256) void score_scatter_k(
    const int* __restrict__ srcA, const int* __restrict__ dstA,
    const float* __restrict__ tA,
    const float* __restrict__ w_time, const float* __restrict__ b_time,
    const unsigned short* __restrict__ zqp,
    const unsigned short* __restrict__ qekp,
    const unsigned short* __restrict__ zkv,
    const int* __restrict__ base, const int* __restrict__ bsum,
    const int* __restrict__ cntr, const int* __restrict__ rank,
    float4* __restrict__ edata2)
{
    const int tid  = threadIdx.x;
    const int w    = tid >> 6;
    const int lane = tid & 63;
    const int eidx = lane & 15;
    const int g    = lane >> 4;
    const int e    = blockIdx.x * 64 + w * 16 + eidx;   // 12500*64 == E

    const int   s = srcA[e];
    const int   d = dstA[e];
    const float tv = tA[e];

    // group g's 16 te params (head g>>1, within-head dim (g&1)*16+i)
    const int hk16 = (g & 1) * 16;
    float wts[16], bts[16];
    #pragma unroll
    for (int i = 0; i < 16; ++i) {
        wts[i] = w_time[hk16 + i];
        bts[i] = b_time[hk16 + i];
    }

    // q/qek dims [16g,16g+16) of dst row; k dims of src row (bf16 pairs)
    const uint4 qa  = *(const uint4*)(zqp  + (size_t)d * 64 + 16 * g);
    const uint4 qb  = *(const uint4*)(zqp  + (size_t)d * 64 + 16 * g + 8);
    const uint4 ea  = *(const uint4*)(qekp + (size_t)d * 64 + 16 * g);
    const uint4 eb  = *(const uint4*)(qekp + (size_t)d * 64 + 16 * g + 8);
    const uint4 ka  = *(const uint4*)(zkv  + (size_t)s * 128 + 16 * g);
    const uint4 kb  = *(const uint4*)(zkv  + (size_t)s * 128 + 16 * g + 8);

    unsigned q2[8]  = {qa.x, qa.y, qa.z, qa.w, qb.x, qb.y, qb.z, qb.w};
    unsigned qe2[8] = {ea.x, ea.y, ea.z, ea.w, eb.x, eb.y, eb.z, eb.w};
    unsigned kk[8]  = {ka.x, ka.y, ka.z, ka.w, kb.x, kb.y, kb.z, kb.w};

    float p = 0.f;
    #pragma unroll
    for (int i2 = 0; i2 < 8; ++i2) {
        const float te0 = __cosf(tv * wts[2*i2]   + bts[2*i2]);
        const float te1 = __cosf(tv * wts[2*i2+1] + bts[2*i2+1]);
        p += te0 * lo16(qe2[i2]) + te1 * hi16(qe2[i2]);
        p += lo16(q2[i2]) * lo16(kk[i2]) + hi16(q2[i2]) * hi16(kk[i2]);
    }
    p += __shfl_xor(p, 16, 64);                 // combine the head's 2 groups
    const float pe  = __expf(p);                // scale pre-folded; all valid
    const float pe1 = __shfl_xor(pe, 32, 64);   // g0 lanes receive head1's pe

    if (g == 0) {
        const int pos = base[d] + bsum[d >> 8]
                      + cntr[((e >> 8) & 7) * N_NODES + d] + rank[e];
        float4 rc;
        rc.x = __int_as_float(s);
        rc.y = tv;
        rc.z = pe;                              // head0
        rc.w = pe1;                             // head1
        edata2[pos] = rc;
    }
}

// ---------------------------------------------------------------------------
// agg_k: one WAVE per node. Chunks of 16 sorted records: coalesced 16B reads
// (prefetched one chunk ahead) -> wave-private LDS -> per-record broadcast:
// v-row gather (64 lanes = full row), av += pe*v, pte += pe*cos(t*w+b).
// lp needs no reduction (every lane in a half accumulates the same pe).
// Epilogue fuses We_v: pte -> LDS, out = skip + (av + pte@We_v)/lp.
// ---------------------------------------------------------------------------
__global__ __launch_bounds__(256) void agg_k(
    const float4* __restrict__ edata2, const int* __restrict__ base,
    const int* __restrict__ bsum, const int* __restrict__ degA,
    const float* __restrict__ w_time, const float* __restrict__ b_time,
    const unsigned short* __restrict__ zkv,
    const float* __restrict__ We_v, float* __restrict__ out)
{
    __shared__ float recs[4][64];               // 1 KB; wave-private strips
    const int tid  = threadIdx.x;
    const int w    = tid >> 6;
    const int lane = tid & 63;
    const int n    = blockIdx.x * 4 + w;

    const int b0  = base[n] + bsum[n >> 8];
    const int deg = degA[n];
    float* rec = &recs[w][0];

    const float wtA = w_time[lane & 31];
    const float btA = b_time[lane & 31];

    float av = 0.f, pte = 0.f, lp = 0.f;

    // prefetch chunk 0
    float4 rc;
    if (lane < 16 && deg > 0)
        rc = edata2[min(b0 + lane, N_EDGES - 1)];

    for (int ch = 0; ch < deg; ch += 16) {
        if (lane < 16) *(float4*)(rec + lane * 4) = rc;
        // prefetch next chunk while processing this one
        const int nch = ch + 16;
        if (lane < 16 && nch < deg)
            rc = edata2[min(b0 + nch + lane, N_EDGES - 1)];

        const int cc = min(16, deg - ch);
        for (int j = 0; j < cc; ++j) {
            const float4 r = *(const float4*)(rec + j * 4);
            const int   srcn = __float_as_int(r.x);
            const float pej  = (lane < 32) ? r.z : r.w;
            const float v    = lo16((unsigned)zkv[(size_t)srcn * 128 + 64 + lane]);
            av  += pej * v;
            pte += pej * __cosf(r.y * wtA + btA);
            lp  += pej;
        }
    }

    // ---- fused We_v epilogue ----
    rec[lane] = pte;                            // rec[h*32+dim] layout
    float wev[32];
    #pragma unroll
    for (int k = 0; k < 32; ++k) wev[k] = We_v[k * 64 + lane];

    const float inv = (lp > 0.f) ? 1.f / lp : 0.f;
    const float* pl = rec + (lane >> 5) * 32;
    float dot = 0.f;
    #pragma unroll
    for (int k = 0; k < 32; ++k) dot += pl[k] * wev[k];

    out[(size_t)n * OUT_DIM + lane] += (av + dot) * inv;   // skip already there
}

extern "C" void kernel_launch(void* const* d_in, const int* in_sizes, int n_in,
                              void* d_out, int out_size, void* d_ws, size_t ws_size,
                              hipStream_t stream) {
    (void)in_sizes; (void)n_in; (void)out_size; (void)ws_size;
    const int*   src    = (const int*)d_in[0];
    const int*   dst    = (const int*)d_in[1];
    const float* t      = (const float*)d_in[2];
    const float* x      = (const float*)d_in[3];
    const float* mem    = (const float*)d_in[4];
    const float* w_time = (const float*)d_in[5];
    const float* b_time = (const float*)d_in[6];
    const float* Wq     = (const float*)d_in[7];
    const float* Wk     = (const float*)d_in[8];
    const float* Wv     = (const float*)d_in[9];
    const float* We_k   = (const float*)d_in[10];
    const float* We_v   = (const float*)d_in[11];
    const float* Wskip  = (const float*)d_in[12];

    // workspace layout (16B-aligned chunks)
    char* p = (char*)d_ws;
    unsigned short* zkv  = (unsigned short*)p; p += (size_t)N_NODES * 128 * 2; // 12.8 MB
    unsigned short* zqp  = (unsigned short*)p; p += (size_t)N_NODES * 64 * 2;  // 6.4 MB
    unsigned short* qekp = (unsigned short*)p; p += (size_t)N_NODES * 64 * 2;  // 6.4 MB
    unsigned short* wtb  = (unsigned short*)p; p += (size_t)5 * 64 * 160 * 2;  // 100 KB
    float4* edata2 = (float4*)p; p += (size_t)N_EDGES * 16;                    // 12.8 MB
    int*  cntr  = (int*)p;   p += (size_t)8 * N_NODES * 4;   // zeroed in prep_k
    int*  rank  = (int*)p;   p += (size_t)N_EDGES * 4;
    int*  base  = (int*)p;   p += (size_t)N_NODES * 4;
    int*  deg   = (int*)p;   p += (size_t)N_NODES * 4;
    int*  bsum  = (int*)p;   p += 256 * 4;
    float* out  = (float*)d_out;

    prep_k   <<<1600, 256, 0, stream>>>(Wq, Wk, Wv, Wskip, We_k, wtb, cntr);
    node_gemm<<<N_NODES / 16, 320, 0, stream>>>(x, mem, wtb, zqp, zkv, qekp, out);
    hist_k   <<<N_EDGES / 256, 256, 0, stream>>>(dst, cntr, rank);
    scan1_k  <<<NB_SCAN, 256, 0, stream>>>(cntr, base, bsum, deg);
    scan2_k  <<<1, 256, 0, stream>>>(bsum);
    score_scatter_k<<<N_EDGES / 64, 256, 0, stream>>>(src, dst, t, w_time, b_time,
                                                      zqp, qekp, zkv, base, bsum,
                                                      cntr, rank, edata2);
    agg_k    <<<N_NODES / 4, 256, 0, stream>>>(edata2, base, bsum, deg,
                                               w_time, b_time, zkv, We_v, out);
}